// Round 1
// baseline (212.369 us; speedup 1.0000x reference)
//
#include <hip/hip_runtime.h>
#include <hip/hip_bf16.h>

#define MAX_N 2048  // LDS capacity: 2048 * 16B = 32 KiB

__device__ __forceinline__ float softplus_f(float x) {
    // matches jax.nn.softplus = logaddexp(x, 0) = max(x,0) + log1p(exp(-|x|))
    return fmaxf(x, 0.0f) + log1pf(expf(-fabsf(x)));
}

__global__ __launch_bounds__(256) void soft_voronoi_kernel(
    const float* __restrict__ positions,   // (N,2)
    const float* __restrict__ activities,  // (N,)
    const float* __restrict__ query,       // (M,2)
    const float* __restrict__ s_ax,
    const float* __restrict__ s_ay,
    const float* __restrict__ s_tx,
    const float* __restrict__ s_ty,
    const float* __restrict__ s_sigma,
    const float* __restrict__ s_beta,
    float* __restrict__ out,
    int N, int M)
{
    __shared__ float4 sn[MAX_N];  // (px, py, act, pad)

    // --- scalars (once per thread; trivial) ---
    const float ax = s_ax[0], ay = s_ay[0], tx = s_tx[0], ty = s_ty[0];
    const float R = softplus_f(s_sigma[0]) + 1e-6f;
    const float b = softplus_f(s_beta[0]) + 1e-6f;
    const float invR2 = 1.0f / (R * R);
    const float LOG2E = 1.4426950408889634f;
    // sigmoid(b*(R-r)) = 1 / (1 + exp(b*(r-R))) = 1 / (1 + exp2(r*A + B))
    const float A = b * LOG2E;
    const float B = -R * b * LOG2E;

    // --- stage neurons into LDS with affine applied ---
    for (int i = threadIdx.x; i < N; i += blockDim.x) {
        float p0 = positions[2 * i + 0];
        float p1 = positions[2 * i + 1];
        float px = fmaf(ax, p0 - 0.5f, tx + 0.5f);
        float py = fmaf(ay, p1 - 0.5f, ty + 0.5f);
        sn[i] = make_float4(px, py, activities[i], 0.0f);
    }
    __syncthreads();

    const int q = blockIdx.x * blockDim.x + threadIdx.x;
    if (q >= M) return;

    const float2 qp = ((const float2*)query)[q];
    const float qx = qp.x, qy = qp.y;

    float num = 0.0f, den = 0.0f;

    #pragma unroll 4
    for (int n = 0; n < N; ++n) {
        float4 s = sn[n];                      // broadcast ds_read_b128
        float dx = qx - s.x;
        float dy = qy - s.y;
        float r2 = fmaf(dx, dx, fmaf(dy, dy, 1e-8f));
        float r  = __builtin_amdgcn_sqrtf(r2);
        // bump = clip(1 - r2/R^2, 0)^10
        float t  = fmaxf(fmaf(-r2, invR2, 1.0f), 0.0f);
        float t2 = t * t;
        float t4 = t2 * t2;
        float t8 = t4 * t4;
        float bump = t8 * t2;
        // mask = sigmoid(b*(R-r))
        float e    = __builtin_amdgcn_exp2f(fmaf(r, A, B));
        float mask = __builtin_amdgcn_rcpf(1.0f + e);
        float k = bump * mask;
        num = fmaf(k, s.z, num);
        den += k;
    }

    out[q] = num / (den + 1e-8f);
}

extern "C" void kernel_launch(void* const* d_in, const int* in_sizes, int n_in,
                              void* d_out, int out_size, void* d_ws, size_t ws_size,
                              hipStream_t stream) {
    const float* positions  = (const float*)d_in[0];
    const float* activities = (const float*)d_in[1];
    const float* query      = (const float*)d_in[2];
    const float* s_ax       = (const float*)d_in[3];
    const float* s_ay       = (const float*)d_in[4];
    const float* s_tx       = (const float*)d_in[5];
    const float* s_ty       = (const float*)d_in[6];
    const float* s_sigma    = (const float*)d_in[7];
    const float* s_beta     = (const float*)d_in[8];

    const int N = in_sizes[0] / 2;   // 1024
    const int M = in_sizes[2] / 2;   // 262144

    const int block = 256;
    const int grid = (M + block - 1) / block;

    soft_voronoi_kernel<<<grid, block, 0, stream>>>(
        positions, activities, query,
        s_ax, s_ay, s_tx, s_ty, s_sigma, s_beta,
        (float*)d_out, N, M);
}

// Round 2
// 163.575 us; speedup vs baseline: 1.2983x; 1.2983x over previous
//
#include <hip/hip_runtime.h>
#include <hip/hip_bf16.h>

#define LUTN 8192   // LUT entries; entry LUTN-1 is the exact-zero guard
#define MAX_N 2048

__device__ __forceinline__ float softplus_f(float x) {
    return fmaxf(x, 0.0f) + log1pf(expf(-fabsf(x)));
}

__device__ __forceinline__ float eval_k(float s, float R, float invR2, float A, float B) {
    // k(s) = clip(1 - s/R^2, 0)^10 * sigmoid(b*(R - sqrt(s)))
    float r  = __builtin_amdgcn_sqrtf(s);
    float t  = fmaxf(fmaf(-s, invR2, 1.0f), 0.0f);
    float t2 = t * t;
    float t4 = t2 * t2;
    float t8 = t4 * t4;
    float bump = t8 * t2;
    float e    = __builtin_amdgcn_exp2f(fmaf(r, A, B));
    float mask = __builtin_amdgcn_rcpf(1.0f + e);
    return bump * mask;
}

// ---------- pre-kernel: build LUT + affine-transformed neurons into d_ws ----------
__global__ __launch_bounds__(256) void prep_kernel(
    const float* __restrict__ positions, const float* __restrict__ activities,
    const float* __restrict__ s_ax, const float* __restrict__ s_ay,
    const float* __restrict__ s_tx, const float* __restrict__ s_ty,
    const float* __restrict__ s_sigma, const float* __restrict__ s_beta,
    float* __restrict__ lut, float4* __restrict__ nrn, int N)
{
    const float R = softplus_f(s_sigma[0]) + 1e-6f;
    const float b = softplus_f(s_beta[0]) + 1e-6f;
    const float invR2 = 1.0f / (R * R);
    const float LOG2E = 1.4426950408889634f;
    const float A = b * LOG2E;
    const float B = -R * b * LOG2E;

    int gid = blockIdx.x * blockDim.x + threadIdx.x;
    if (gid < LUTN) {
        float k = 0.0f;
        if (gid < LUTN - 1) {
            // cell i covers [i*h, (i+1)*h), h = R^2/(LUTN-1); sample center
            float h = (R * R) / (float)(LUTN - 1);
            float s = ((float)gid + 0.5f) * h;
            k = eval_k(s, R, invR2, A, B);
        }
        lut[gid] = k;
    }
    int j = gid - LUTN;
    if (j >= 0 && j < N) {
        const float ax = s_ax[0], ay = s_ay[0], tx = s_tx[0], ty = s_ty[0];
        float px = fmaf(ax, positions[2 * j + 0] - 0.5f, tx + 0.5f);
        float py = fmaf(ay, positions[2 * j + 1] - 0.5f, ty + 0.5f);
        nrn[j] = make_float4(px, py, activities[j], 0.0f);
    }
}

// ---------- main kernel: LUT gather ----------
__global__ __launch_bounds__(256) void soft_voronoi_lut(
    const float* __restrict__ lut_g, const float4* __restrict__ nrn,
    const float* __restrict__ query, const float* __restrict__ s_sigma,
    float* __restrict__ out, int N, int M)
{
    __shared__ float lut[LUTN];

    // coalesced LUT copy global -> LDS (2048 float4 / 256 threads = 8 each)
    {
        const float4* lg4 = (const float4*)lut_g;
        float4* ls4 = (float4*)lut;
        #pragma unroll
        for (int i = 0; i < LUTN / 4 / 256; ++i)
            ls4[threadIdx.x + i * 256] = lg4[threadIdx.x + i * 256];
    }
    __syncthreads();

    const float R = softplus_f(s_sigma[0]) + 1e-6f;
    const float scale = (float)(LUTN - 1) / (R * R);
    const float fmax_idx = (float)(LUTN - 1);

    const int q = blockIdx.x * blockDim.x + threadIdx.x;
    if (q >= M) return;

    const float2 qp = ((const float2*)query)[q];
    const float qx = qp.x, qy = qp.y;

    float num = 0.0f, den = 0.0f;

    #pragma unroll 8
    for (int n = 0; n < N; ++n) {
        float4 s = nrn[n];                 // uniform index -> s_load_dwordx4
        float dx = qx - s.x;
        float dy = qy - s.y;
        float r2 = fmaf(dx, dx, fmaf(dy, dy, 1e-8f));
        float fidx = fminf(r2 * scale, fmax_idx);
        int idx = (int)fidx;
        float k = lut[idx];                // random-index ds_read_b32
        num = fmaf(k, s.z, num);
        den += k;
    }

    out[q] = num / (den + 1e-8f);
}

// ---------- fallback (no workspace): round-1 direct kernel ----------
__global__ __launch_bounds__(256) void soft_voronoi_direct(
    const float* __restrict__ positions, const float* __restrict__ activities,
    const float* __restrict__ query,
    const float* __restrict__ s_ax, const float* __restrict__ s_ay,
    const float* __restrict__ s_tx, const float* __restrict__ s_ty,
    const float* __restrict__ s_sigma, const float* __restrict__ s_beta,
    float* __restrict__ out, int N, int M)
{
    __shared__ float4 sn[MAX_N];
    const float ax = s_ax[0], ay = s_ay[0], tx = s_tx[0], ty = s_ty[0];
    const float R = softplus_f(s_sigma[0]) + 1e-6f;
    const float b = softplus_f(s_beta[0]) + 1e-6f;
    const float invR2 = 1.0f / (R * R);
    const float LOG2E = 1.4426950408889634f;
    const float A = b * LOG2E;
    const float B = -R * b * LOG2E;

    for (int i = threadIdx.x; i < N; i += blockDim.x) {
        float px = fmaf(ax, positions[2 * i + 0] - 0.5f, tx + 0.5f);
        float py = fmaf(ay, positions[2 * i + 1] - 0.5f, ty + 0.5f);
        sn[i] = make_float4(px, py, activities[i], 0.0f);
    }
    __syncthreads();

    const int q = blockIdx.x * blockDim.x + threadIdx.x;
    if (q >= M) return;
    const float2 qp = ((const float2*)query)[q];
    float num = 0.0f, den = 0.0f;
    #pragma unroll 4
    for (int n = 0; n < N; ++n) {
        float4 s = sn[n];
        float dx = qp.x - s.x;
        float dy = qp.y - s.y;
        float r2 = fmaf(dx, dx, fmaf(dy, dy, 1e-8f));
        float k = eval_k(r2, R, invR2, A, B);
        num = fmaf(k, s.z, num);
        den += k;
    }
    out[q] = num / (den + 1e-8f);
}

extern "C" void kernel_launch(void* const* d_in, const int* in_sizes, int n_in,
                              void* d_out, int out_size, void* d_ws, size_t ws_size,
                              hipStream_t stream) {
    const float* positions  = (const float*)d_in[0];
    const float* activities = (const float*)d_in[1];
    const float* query      = (const float*)d_in[2];
    const float* s_ax       = (const float*)d_in[3];
    const float* s_ay       = (const float*)d_in[4];
    const float* s_tx       = (const float*)d_in[5];
    const float* s_ty       = (const float*)d_in[6];
    const float* s_sigma    = (const float*)d_in[7];
    const float* s_beta     = (const float*)d_in[8];

    const int N = in_sizes[0] / 2;   // 1024
    const int M = in_sizes[2] / 2;   // 262144

    const int block = 256;
    const int grid = (M + block - 1) / block;

    const size_t need = (size_t)LUTN * 4 + (size_t)N * 16;
    if (ws_size >= need) {
        float*  lut = (float*)d_ws;
        float4* nrn = (float4*)((char*)d_ws + (size_t)LUTN * 4);
        const int prep_grid = (LUTN + N + block - 1) / block;
        prep_kernel<<<prep_grid, block, 0, stream>>>(
            positions, activities, s_ax, s_ay, s_tx, s_ty, s_sigma, s_beta,
            lut, nrn, N);
        soft_voronoi_lut<<<grid, block, 0, stream>>>(
            lut, nrn, query, s_sigma, (float*)d_out, N, M);
    } else {
        soft_voronoi_direct<<<grid, block, 0, stream>>>(
            positions, activities, query,
            s_ax, s_ay, s_tx, s_ty, s_sigma, s_beta,
            (float*)d_out, N, M);
    }
}